// Round 6
// baseline (110.382 us; speedup 1.0000x reference)
//
#include <hip/hip_runtime.h>

#define MDIM 512
#define LCH  31
#define CDIM 542   // MD + L - 1
#define INW  1024
#define TN   64                 // output n-columns per block (k1)
#define NELEM (MDIM*MDIM*LCH)   // 8126464
#define GB3  2048               // k3/k4 grid blocks

// ws layout (floats): Xm[m][l][n], yn[m][c], pmaxY[512], pmaxT[2048], scl[2]
#define XM_OFF  0
#define YN_OFF  (MDIM*LCH*MDIM)
#define PMY_OFF (YN_OFF + MDIM*CDIM)
#define PMT_OFF (PMY_OFF + MDIM)
#define SCL_OFF (PMT_OFF + GB3)

// K1: fused bilinear-resize + l-conv + H-mult.
// Block = (m, n-tile of 64). Phase 1: 16 global_load_dwordx4 issued
// back-to-back per thread (MLP — the round-5 kernel serialized them at
// VGPR=16 and was latency-bound). Addresses are clamped instead of
// branch-guarded: every out-of-range tile entry is consumed only with a
// zero horizontal weight (col -1 <-> wx0=0 at n=0; col 1024 <-> wx3=0 at
// n=511), so clamped-garbage (finite) values are harmless.
__global__ __launch_bounds__(256) void k1_fused(const float* __restrict__ X,
                                                const float* __restrict__ H,
                                                float* __restrict__ Xm) {
    __shared__ float xv[4096];          // 16 KB; tile uses [0,4032), rest pad

    const int m     = blockIdx.x >> 3;  // bid = m*8 + ntile
    const int ntile = blockIdx.x & 7;
    const int n0    = ntile * TN;
    const int t     = threadIdx.x;

    float wy0=0.125f, wy1=0.375f, wy2=0.375f, wy3=0.125f;
    if (m == 0)        wy0 = 0.f;
    if (m == MDIM-1)   wy3 = 0.f;
    if (m == 0 || m == MDIM-1) {
        const float inv = 1.0f/0.875f;
        wy0*=inv; wy1*=inv; wy2*=inv; wy3*=inv;
    }
    const int rr0 = 2*m - 1;
    const int RS  = INW*LCH;            // floats per input row = 31744
    const float* xr0 = X + (size_t)min(max(rr0+0,0),INW-1)*RS;
    const float* xr1 = X + (size_t)(rr0+1)*RS;
    const float* xr2 = X + (size_t)(rr0+2)*RS;
    const float* xr3 = X + (size_t)min(max(rr0+3,0),INW-1)*RS;

    const int qa = (2*n0 - 1)*LCH - 1;  // float4-aligned tile start (q offset)

    // phase 1: vertical 4-tap resize. All 16 loads issued before any use.
    int qs[4];
    #pragma unroll
    for (int j = 0; j < 4; ++j) {
        int q0 = qa + 4*(t + 256*j);
        qs[j] = min(max(q0, 0), RS - 4);   // clamp; OOB lanes feed zero-weight taps
    }
    float4 A[4], B[4], C[4], D[4];
    #pragma unroll
    for (int j = 0; j < 4; ++j) A[j] = *(const float4*)(xr0 + qs[j]);
    #pragma unroll
    for (int j = 0; j < 4; ++j) B[j] = *(const float4*)(xr1 + qs[j]);
    #pragma unroll
    for (int j = 0; j < 4; ++j) C[j] = *(const float4*)(xr2 + qs[j]);
    #pragma unroll
    for (int j = 0; j < 4; ++j) D[j] = *(const float4*)(xr3 + qs[j]);
    #pragma unroll
    for (int j = 0; j < 4; ++j) {
        float4 a;
        a.x = fmaf(wy0,A[j].x, fmaf(wy1,B[j].x, fmaf(wy2,C[j].x, wy3*D[j].x)));
        a.y = fmaf(wy0,A[j].y, fmaf(wy1,B[j].y, fmaf(wy2,C[j].y, wy3*D[j].y)));
        a.z = fmaf(wy0,A[j].z, fmaf(wy1,B[j].z, fmaf(wy2,C[j].z, wy3*D[j].z)));
        a.w = fmaf(wy0,A[j].w, fmaf(wy1,B[j].w, fmaf(wy2,C[j].w, wy3*D[j].w)));
        *(float4*)&xv[4*(t + 256*j)] = a;
    }
    __syncthreads();

    // phase 2: l-conv (in-LDS taps) + horizontal 4-tap + H multiply
    const float* Hrow = H + ((size_t)m*MDIM + n0)*LCH;
    float* Xrow = Xm + (size_t)m*LCH*MDIM + n0;
    for (int idx = t; idx < LCH*TN; idx += 256) {
        const int l  = idx >> 6;        // 0..30
        const int nl = idx & (TN-1);
        const int n  = n0 + nl;
        float wx0=0.125f, wx1=0.375f, wx2=0.375f, wx3=0.125f;
        if (n == 0)        wx0 = 0.f;
        if (n == MDIM-1)   wx3 = 0.f;
        if (n == 0 || n == MDIM-1) {
            const float inv = 1.0f/0.875f;
            wx0*=inv; wx1*=inv; wx2*=inv; wx3*=inv;
        }
        const float wb[4] = {wx0, wx1, wx2, wx3};
        // xv[i] holds q = qa + i; tap (col=2n-1+b, l) at i = 2nl*31 + l + 1 + 31b
        const float* p0 = xv + 2*nl*LCH + l + 1;
        float acc = 0.f;
        #pragma unroll
        for (int b = 0; b < 4; ++b) {
            const float* p = p0 + b*LCH;
            float c = 0.5f*p[0];
            if (l > 0)      c += 0.25f*p[-1];
            if (l < LCH-1)  c += 0.25f*p[1];
            acc = fmaf(wb[b], c, acc);
        }
        Xrow[(size_t)l*MDIM + nl] = acc * Hrow[nl*LCH + l];
    }
}

// K2: yn[m,c] = sum_i Xm[m][i][c-i]; per-row max -> pmaxY[m] (plain store).
__global__ __launch_bounds__(256) void k2_shiftsum(const float* __restrict__ Xm,
                                                   float* __restrict__ yn,
                                                   float* __restrict__ pmaxY) {
    const int m = blockIdx.x;
    const float* base = Xm + (size_t)m*LCH*MDIM;
    float lmax = -3.4e38f;
    for (int c = threadIdx.x; c < CDIM; c += 256) {
        float s = 0.f;
        const int ilo = max(0, c - (MDIM-1));
        const int ihi = min(LCH-1, c);
        for (int i = ilo; i <= ihi; ++i)
            s += base[(size_t)i*MDIM + (c - i)];
        yn[m*CDIM + c] = s;
        lmax = fmaxf(lmax, s);
    }
    __shared__ float red[256];
    red[threadIdx.x] = lmax; __syncthreads();
    for (int s = 128; s > 0; s >>= 1) {
        if ((int)threadIdx.x < s)
            red[threadIdx.x] = fmaxf(red[threadIdx.x], red[threadIdx.x+s]);
        __syncthreads();
    }
    if (threadIdx.x == 0) pmaxY[m] = red[0];
}

// Reduce n partial maxes -> out_inv[0] = 1/max. Single block, deterministic.
__global__ __launch_bounds__(256) void kmax_reduce(const float* __restrict__ pmax,
                                                   int n,
                                                   float* __restrict__ out_inv) {
    __shared__ float red[256];
    float lmax = -3.4e38f;
    for (int i = threadIdx.x; i < n; i += 256)
        lmax = fmaxf(lmax, pmax[i]);
    red[threadIdx.x] = lmax; __syncthreads();
    for (int s = 128; s > 0; s >>= 1) {
        if ((int)threadIdx.x < s)
            red[threadIdx.x] = fmaxf(red[threadIdx.x], red[threadIdx.x+s]);
        __syncthreads();
    }
    if (threadIdx.x == 0) out_inv[0] = 1.0f / red[0];
}

// t(idx) = H[idx] * conv_i(yn/My - y at c=n+i)  -- shared by k3 (max) and k4 (write)
__device__ __forceinline__ float t_elem(int idx,
                                        const float* __restrict__ yn,
                                        const float* __restrict__ y,
                                        const float* __restrict__ H,
                                        float inv) {
    const int i    = idx % LCH;
    const int rest = idx / LCH;
    const int n    = rest & (MDIM-1);
    const int m    = rest >> 9;
    const int c    = n + i;
    const float* ynr = yn + (size_t)m*CDIM;
    const float* yr  = y  + (size_t)m*CDIM;
    float v = 0.5f * (ynr[c]*inv - yr[c]);
    if (i > 0)     v += 0.25f*(ynr[c-1]*inv - yr[c-1]);
    if (i < LCH-1) v += 0.25f*(ynr[c+1]*inv - yr[c+1]);
    return H[idx]*v;
}

// K3: block-max of t over grid-stride range -> pmaxT[bid]. No stores of t.
__global__ __launch_bounds__(256) void k3_max(const float* __restrict__ yn,
                                              const float* __restrict__ y,
                                              const float* __restrict__ H,
                                              const float* __restrict__ scl,
                                              float* __restrict__ pmaxT) {
    const float inv = scl[0];
    float lmax = -3.4e38f;
    for (int idx = blockIdx.x*blockDim.x + threadIdx.x; idx < NELEM;
         idx += GB3*256)
        lmax = fmaxf(lmax, t_elem(idx, yn, y, H, inv));
    __shared__ float red[256];
    red[threadIdx.x] = lmax; __syncthreads();
    for (int s = 128; s > 0; s >>= 1) {
        if ((int)threadIdx.x < s)
            red[threadIdx.x] = fmaxf(red[threadIdx.x], red[threadIdx.x+s]);
        __syncthreads();
    }
    if (threadIdx.x == 0) pmaxT[blockIdx.x] = red[0];
}

// K4: recompute t, scale by 1/maxT, write out (coalesced, single pass).
__global__ __launch_bounds__(256) void k4_out(const float* __restrict__ yn,
                                              const float* __restrict__ y,
                                              const float* __restrict__ H,
                                              const float* __restrict__ scl,
                                              float* __restrict__ out) {
    const float inv  = scl[0];
    const float invT = scl[1];
    for (int idx = blockIdx.x*blockDim.x + threadIdx.x; idx < NELEM;
         idx += GB3*256)
        out[idx] = t_elem(idx, yn, y, H, inv) * invT;
}

extern "C" void kernel_launch(void* const* d_in, const int* in_sizes, int n_in,
                              void* d_out, int out_size, void* d_ws, size_t ws_size,
                              hipStream_t stream) {
    const float* X = (const float*)d_in[0];
    const float* y = (const float*)d_in[1];
    const float* H = (const float*)d_in[2];
    float* out = (float*)d_out;
    float* ws  = (float*)d_ws;

    float* Xm    = ws + XM_OFF;
    float* yn    = ws + YN_OFF;
    float* pmaxY = ws + PMY_OFF;
    float* pmaxT = ws + PMT_OFF;
    float* scl   = ws + SCL_OFF;   // [0]=1/maxY, [1]=1/maxT

    k1_fused<<<MDIM*8, 256, 0, stream>>>(X, H, Xm);                 // 4096 blocks
    k2_shiftsum<<<MDIM, 256, 0, stream>>>(Xm, yn, pmaxY);           // 512 blocks
    kmax_reduce<<<1, 256, 0, stream>>>(pmaxY, MDIM, scl);
    k3_max<<<GB3, 256, 0, stream>>>(yn, y, H, scl, pmaxT);          // 2048 blocks
    kmax_reduce<<<1, 256, 0, stream>>>(pmaxT, GB3, scl + 1);
    k4_out<<<GB3, 256, 0, stream>>>(yn, y, H, scl, out);
}